// Round 1
// baseline (191.316 us; speedup 1.0000x reference)
//
#include <hip/hip_runtime.h>
#include <math.h>

// ---------------------------------------------------------------------------
// ConvLogicNetCIFAR forward: 4 x (conv_tree + orpool) + 3 x difflogic FC +
// class-sum.  All gates are  c0 + c1*a + c2*b + c3*a*b  with c = softmax(w)@COEF.
// NOTE reference quirk: off = 2^level - 1 => coef slices [0:4],[1:3],[3:4];
// only coef rows 0..3 per conv channel are used (rows 1,2,3 reused across levels).
// ---------------------------------------------------------------------------

#define B_SZ 128

__constant__ float c_coef_tbl[16][4] = {
    {0, 0, 0, 0}, {0, 0, 0, 1}, {0, 1, 0, -1}, {0, 1, 0, 0},
    {0, 0, 1, -1}, {0, 0, 1, 0}, {0, 1, 1, -2}, {0, 1, 1, -1},
    {1, -1, -1, 1}, {1, -1, -1, 2}, {1, 0, -1, 0}, {1, 0, -1, 1},
    {1, -1, 0, 0}, {1, -1, 0, 1}, {1, 0, 0, -1}, {1, 0, 0, 0}};

// softmax(w_row) @ COEF -> 4 coefficients per gate.
// conv==1: gate g => weight row (g/4)*7 + (g%4)   (w is (OC,7,16), rows 0..3 used)
// conv==0: gate g => weight row g                 (w is (OD,16))
__global__ void make_coef(const float* __restrict__ w, float* __restrict__ coef,
                          int n, int conv) {
  int g = blockIdx.x * blockDim.x + threadIdx.x;
  if (g >= n) return;
  int row = conv ? ((g >> 2) * 7 + (g & 3)) : g;
  const float* wr = w + row * 16;
  float m = -1e30f;
#pragma unroll
  for (int k = 0; k < 16; ++k) m = fmaxf(m, wr[k]);
  float e[16], s = 0.f;
#pragma unroll
  for (int k = 0; k < 16; ++k) { e[k] = __expf(wr[k] - m); s += e[k]; }
  float inv = 1.f / s;
  float c0 = 0.f, c1 = 0.f, c2 = 0.f, c3 = 0.f;
#pragma unroll
  for (int k = 0; k < 16; ++k) {
    c0 += e[k] * c_coef_tbl[k][0];
    c1 += e[k] * c_coef_tbl[k][1];
    c2 += e[k] * c_coef_tbl[k][2];
    c3 += e[k] * c_coef_tbl[k][3];
  }
  float4* o = (float4*)coef;
  o[g] = make_float4(c0 * inv, c1 * inv, c2 * inv, c3 * inv);
}

__device__ __forceinline__ float gate_eval(float4 c, float a, float b) {
  return c.x + c.y * a + c.z * b + c.w * (a * b);
}

// One thread per pooled output (b, oc, ph, pw).  tid order: pw,ph,b,oc (oc
// uniform per 256-block for all stage shapes).
// BIN: input is raw x (B,3,H,W); binarize channel c'=k/9 as x[c'%3] > (c'/3+1)/4.
// FEATMAJOR: write out[(oc*PH*PW + ph*PW + pw)*B + b]  (fuses final reshape,
// feature-major for the FC gathers).
template <int BIN, int FEATMAJOR>
__global__ void conv_tree_pool(const float* __restrict__ in,
                               const float* __restrict__ coef,
                               const int* __restrict__ leaf,
                               float* __restrict__ out,
                               int C, int H, int W, int OC) {
  int tid = blockIdx.x * blockDim.x + threadIdx.x;
  int PH = H >> 1, PW = W >> 1;
  int pw = tid % PW;
  int t = tid / PW;
  int ph = t % PH;
  t /= PH;
  int b = t % B_SZ;
  int oc = t / B_SZ;
  if (oc >= OC) return;

  int lf[8];
#pragma unroll
  for (int l = 0; l < 8; ++l) lf[l] = leaf[oc * 8 + l];
  const float4* cf = (const float4*)coef;
  float4 c0 = cf[oc * 4 + 0];
  float4 c1 = cf[oc * 4 + 1];
  float4 c2 = cf[oc * 4 + 2];
  float4 c3 = cf[oc * 4 + 3];

  float best = -INFINITY;
#pragma unroll
  for (int py = 0; py < 2; ++py) {
#pragma unroll
    for (int px = 0; px < 2; ++px) {
      int i = 2 * ph + py, j = 2 * pw + px;
      float lv[8];
#pragma unroll
      for (int l = 0; l < 8; ++l) {
        int k = lf[l];
        int c = k / 9;
        int p = k - 9 * c;
        int di = p / 3;
        int dj = p - 3 * di;
        int ii = i + di - 1, jj = j + dj - 1;
        float v = 0.f;
        if ((unsigned)ii < (unsigned)H && (unsigned)jj < (unsigned)W) {
          if (BIN) {
            int sc = c % 3;
            float thr = (float)(c / 3 + 1) * 0.25f;
            v = (in[((b * 3 + sc) * H + ii) * W + jj] > thr) ? 1.f : 0.f;
          } else {
            v = in[((b * C + c) * H + ii) * W + jj];
          }
        }
        lv[l] = v;
      }
      // level 0: coef rows 0..3
      float t0 = gate_eval(c0, lv[0], lv[1]);
      float t1 = gate_eval(c1, lv[2], lv[3]);
      float t2 = gate_eval(c2, lv[4], lv[5]);
      float t3 = gate_eval(c3, lv[6], lv[7]);
      // level 1: coef rows 1..2 (reference off = 2^1-1)
      float u0 = gate_eval(c1, t0, t1);
      float u1 = gate_eval(c2, t2, t3);
      // level 2: coef row 3
      float o = gate_eval(c3, u0, u1);
      best = fmaxf(best, o);
    }
  }
  if (FEATMAJOR) {
    out[(oc * (PH * PW) + ph * PW + pw) * B_SZ + b] = best;
  } else {
    out[((b * OC + oc) * PH + ph) * PW + pw] = best;
  }
}

// Activations feature-major [feat][128].  2 outputs per 256-thread block.
__global__ void difflogic_fc(const float* __restrict__ xin,
                             const float* __restrict__ coef,
                             const int* __restrict__ ca,
                             const int* __restrict__ cb,
                             float* __restrict__ out, int OD) {
  int o = blockIdx.x * 2 + (threadIdx.x >> 7);
  int b = threadIdx.x & 127;
  if (o >= OD) return;
  int ia = ca[o], ib = cb[o];
  float4 c = ((const float4*)coef)[o];
  float xa = xin[ia * B_SZ + b];
  float xb = xin[ib * B_SZ + b];
  out[o * B_SZ + b] = c.x + c.y * xa + c.z * xb + c.w * (xa * xb);
}

__global__ void zero_out(float* out, int n) {
  int i = blockIdx.x * blockDim.x + threadIdx.x;
  if (i < n) out[i] = 0.f;
}

// fc3: [10240][128] feature-major.  out[b*10+cls] = sum_t fc3[cls*1024+t][b]/10
// grid = 10*32 blocks (cls, chunk of 32 features), 128 threads = batch lane.
__global__ void reduce_cls(const float* __restrict__ fc3, float* __restrict__ out) {
  int cls = blockIdx.x >> 5;
  int chunk = blockIdx.x & 31;
  int b = threadIdx.x;
  const float* base = fc3 + (cls * 1024 + chunk * 32) * B_SZ + b;
  float s = 0.f;
#pragma unroll
  for (int t = 0; t < 32; ++t) s += base[t * B_SZ];
  atomicAdd(&out[b * 10 + cls], s * 0.1f);
}

extern "C" void kernel_launch(void* const* d_in, const int* in_sizes, int n_in,
                              void* d_out, int out_size, void* d_ws, size_t ws_size,
                              hipStream_t stream) {
  const float* x   = (const float*)d_in[0];
  const float* w1  = (const float*)d_in[1];
  const float* w2  = (const float*)d_in[2];
  const float* w3  = (const float*)d_in[3];
  const float* w4  = (const float*)d_in[4];
  const float* fw1 = (const float*)d_in[5];
  const float* fw2 = (const float*)d_in[6];
  const float* fw3 = (const float*)d_in[7];
  const int* l1  = (const int*)d_in[8];
  const int* l2  = (const int*)d_in[9];
  const int* l3  = (const int*)d_in[10];
  const int* l4  = (const int*)d_in[11];
  const int* ca1 = (const int*)d_in[12];
  const int* cb1 = (const int*)d_in[13];
  const int* ca2 = (const int*)d_in[14];
  const int* cb2 = (const int*)d_in[15];
  const int* ca3 = (const int*)d_in[16];
  const int* cb3 = (const int*)d_in[17];

  float* ws = (float*)d_ws;
  // coef tables (floats): conv oc counts 32/128/512/1024, 16 floats each oc
  float* cC1 = ws;                    // 32*16   = 512
  float* cC2 = cC1 + 512;             // 128*16  = 2048
  float* cC3 = cC2 + 2048;            // 512*16  = 8192
  float* cC4 = cC3 + 8192;            // 1024*16 = 16384
  float* cF1 = cC4 + 16384;           // 40960*4 = 163840
  float* cF2 = cF1 + 163840;          // 20480*4 = 81920
  float* cF3 = cF2 + 81920;           // 10240*4 = 40960
  float* bufA = cF3 + 40960;          // 5,242,880 floats
  float* bufB = bufA + 5242880;       // 2,621,440 floats
  // total = 8,178,176 floats = ~32.7 MB

  // gate coefficients
  make_coef<<<(128 + 255) / 256, 256, 0, stream>>>(w1, cC1, 32 * 4, 1);
  make_coef<<<(512 + 255) / 256, 256, 0, stream>>>(w2, cC2, 128 * 4, 1);
  make_coef<<<(2048 + 255) / 256, 256, 0, stream>>>(w3, cC3, 512 * 4, 1);
  make_coef<<<(4096 + 255) / 256, 256, 0, stream>>>(w4, cC4, 1024 * 4, 1);
  make_coef<<<(40960 + 255) / 256, 256, 0, stream>>>(fw1, cF1, 40960, 0);
  make_coef<<<(20480 + 255) / 256, 256, 0, stream>>>(fw2, cF2, 20480, 0);
  make_coef<<<(10240 + 255) / 256, 256, 0, stream>>>(fw3, cF3, 10240, 0);

  // conv stages: threads = OC*B*PH*PW
  conv_tree_pool<1, 0><<<4096, 256, 0, stream>>>(x,    cC1, l1, bufA,   9, 32, 32,   32);
  conv_tree_pool<0, 0><<<4096, 256, 0, stream>>>(bufA, cC2, l2, bufB,  32, 16, 16,  128);
  conv_tree_pool<0, 0><<<4096, 256, 0, stream>>>(bufB, cC3, l3, bufA, 128,  8,  8,  512);
  conv_tree_pool<0, 1><<<2048, 256, 0, stream>>>(bufA, cC4, l4, bufB, 512,  4,  4, 1024);

  // FC difflogic chain (feature-major [feat][128])
  difflogic_fc<<<20480, 256, 0, stream>>>(bufB, cF1, ca1, cb1, bufA, 40960);
  difflogic_fc<<<10240, 256, 0, stream>>>(bufA, cF2, ca2, cb2, bufB, 20480);
  difflogic_fc<<<5120, 256, 0, stream>>>(bufB, cF3, ca3, cb3, bufA, 10240);

  // class reduction
  zero_out<<<5, 256, 0, stream>>>((float*)d_out, 1280);
  reduce_cls<<<320, 128, 0, stream>>>(bufA, (float*)d_out);
}

// Round 2
// 113.236 us; speedup vs baseline: 1.6895x; 1.6895x over previous
//
#include <hip/hip_runtime.h>
#include <math.h>

// ---------------------------------------------------------------------------
// ConvLogicNetCIFAR forward. R2: feature-major [feat][B=128] layout EVERYWHERE
// so every gather is a coalesced 512B segment per 128-thread group.
// Gates: c0 + c1*a + c2*b + c3*a*b, c = softmax(w)@COEF.
// Tree quirk: off = 2^level-1 => level0 rows 0..3, level1 rows 1..2, level2 row 3.
// ---------------------------------------------------------------------------

#define B_SZ 128

__constant__ float c_coef_tbl[16][4] = {
    {0, 0, 0, 0}, {0, 0, 0, 1}, {0, 1, 0, -1}, {0, 1, 0, 0},
    {0, 0, 1, -1}, {0, 0, 1, 0}, {0, 1, 1, -2}, {0, 1, 1, -1},
    {1, -1, -1, 1}, {1, -1, -1, 2}, {1, 0, -1, 0}, {1, 0, -1, 1},
    {1, -1, 0, 0}, {1, -1, 0, 1}, {1, 0, 0, -1}, {1, 0, 0, 0}};

// One kernel for ALL gate-coef tables, written contiguously as float4[78464].
// Ranges: conv tables (4 gates per oc, weight row (oc)*7 + gate): w1[0,128),
// w2[128,640), w3[640,2688), w4[2688,6784); fc: fw1[6784,47744),
// fw2[47744,68224), fw3[68224,78464).  Also zeroes d_out (runs first on stream).
__global__ void make_coef_all(const float* __restrict__ w1, const float* __restrict__ w2,
                              const float* __restrict__ w3, const float* __restrict__ w4,
                              const float* __restrict__ f1, const float* __restrict__ f2,
                              const float* __restrict__ f3,
                              float* __restrict__ coef, float* __restrict__ out_zero) {
  int g = blockIdx.x * blockDim.x + threadIdx.x;
  if (g < 1280) out_zero[g] = 0.f;
  if (g >= 78464) return;
  const float* wr;
  if (g < 6784) {  // conv gates: row = oc*7 + (g&3)
    int gg; const float* w;
    if (g < 128)       { gg = g;        w = w1; }
    else if (g < 640)  { gg = g - 128;  w = w2; }
    else if (g < 2688) { gg = g - 640;  w = w3; }
    else               { gg = g - 2688; w = w4; }
    wr = w + ((gg >> 2) * 7 + (gg & 3)) * 16;
  } else {
    int gg;
    if (g < 47744)      { gg = g - 6784;  wr = f1 + gg * 16; }
    else if (g < 68224) { gg = g - 47744; wr = f2 + gg * 16; }
    else                { gg = g - 68224; wr = f3 + gg * 16; }
  }
  float m = -1e30f;
#pragma unroll
  for (int k = 0; k < 16; ++k) m = fmaxf(m, wr[k]);
  float e[16], s = 0.f;
#pragma unroll
  for (int k = 0; k < 16; ++k) { e[k] = __expf(wr[k] - m); s += e[k]; }
  float inv = 1.f / s;
  float c0 = 0.f, c1 = 0.f, c2 = 0.f, c3 = 0.f;
#pragma unroll
  for (int k = 0; k < 16; ++k) {
    c0 += e[k] * c_coef_tbl[k][0];
    c1 += e[k] * c_coef_tbl[k][1];
    c2 += e[k] * c_coef_tbl[k][2];
    c3 += e[k] * c_coef_tbl[k][3];
  }
  ((float4*)coef)[g] = make_float4(c0 * inv, c1 * inv, c2 * inv, c3 * inv);
}

// x (128,3,32,32) -> xb [9][1024][128] binarized, via LDS transpose.
// grid = 3 chan * 16 pos-tiles * 2 b-tiles = 96 blocks, 256 threads.
__global__ void binarize_transpose(const float* __restrict__ x, float* __restrict__ out) {
  __shared__ float tile[64][65];
  int blk = blockIdx.x;
  int c = blk % 3; blk /= 3;
  int pt = blk % 16; blk /= 16;
  int b0 = blk * 64, p0 = pt * 64;
  int tp = threadIdx.x & 63;
  int tr = threadIdx.x >> 6;
#pragma unroll
  for (int r = 0; r < 16; ++r) {
    int bl = r * 4 + tr;
    tile[bl][tp] = x[((b0 + bl) * 3 + c) * 1024 + p0 + tp];  // coalesced read
  }
  __syncthreads();
  int bl = threadIdx.x & 63;
  int pr = threadIdx.x >> 6;
#pragma unroll
  for (int r = 0; r < 16; ++r) {
    int pl = r * 4 + pr;
    float v = tile[bl][pl];  // stride-65 => conflict-free
#pragma unroll
    for (int th = 0; th < 3; ++th) {
      float thr = (float)(th + 1) * 0.25f;
      out[((th * 3 + c) * 1024 + p0 + pl) * B_SZ + b0 + bl] = (v > thr) ? 1.f : 0.f;
    }
  }
}

__device__ __forceinline__ float gate_eval(float4 c, float a, float b) {
  return c.x + c.y * a + c.z * b + c.w * (a * b);
}

// Feature-major conv tree + orpool.  in [C][H][W][128], out [OC][PH][PW][128].
// tid: b fast (128-group shares oc,ph,pw -> all gathers coalesced 512B).
__global__ void conv_tree_pool_fm(const float* __restrict__ in,
                                  const float* __restrict__ coef,
                                  const int* __restrict__ leaf,
                                  float* __restrict__ out,
                                  int C, int H, int W, int OC) {
  int tid = blockIdx.x * blockDim.x + threadIdx.x;
  int b = tid & 127;
  int t = tid >> 7;
  int PH = H >> 1, PW = W >> 1;
  int pw = t % PW; t /= PW;
  int ph = t % PH; t /= PH;
  int oc = t;
  if (oc >= OC) return;

  int lf[8];
#pragma unroll
  for (int l = 0; l < 8; ++l) lf[l] = leaf[oc * 8 + l];
  const float4* cf = (const float4*)coef;
  float4 c0 = cf[oc * 4 + 0];
  float4 c1 = cf[oc * 4 + 1];
  float4 c2 = cf[oc * 4 + 2];
  float4 c3 = cf[oc * 4 + 3];

  float best = -INFINITY;
#pragma unroll
  for (int py = 0; py < 2; ++py) {
#pragma unroll
    for (int px = 0; px < 2; ++px) {
      int i = 2 * ph + py, j = 2 * pw + px;
      float lv[8];
#pragma unroll
      for (int l = 0; l < 8; ++l) {
        int k = lf[l];
        int c = k / 9;
        int p = k - 9 * c;
        int di = p / 3;
        int dj = p - 3 * di;
        int ii = i + di - 1, jj = j + dj - 1;
        float v = 0.f;
        if ((unsigned)ii < (unsigned)H && (unsigned)jj < (unsigned)W)
          v = in[((c * H + ii) * W + jj) * B_SZ + b];
        lv[l] = v;
      }
      float t0 = gate_eval(c0, lv[0], lv[1]);
      float t1 = gate_eval(c1, lv[2], lv[3]);
      float t2 = gate_eval(c2, lv[4], lv[5]);
      float t3 = gate_eval(c3, lv[6], lv[7]);
      float u0 = gate_eval(c1, t0, t1);
      float u1 = gate_eval(c2, t2, t3);
      best = fmaxf(best, gate_eval(c3, u0, u1));
    }
  }
  out[(oc * (PH * PW) + ph * PW + pw) * B_SZ + b] = best;
}

// Activations feature-major [feat][128]. 2 outputs per 256-thread block.
__global__ void difflogic_fc(const float* __restrict__ xin,
                             const float* __restrict__ coef,
                             const int* __restrict__ ca,
                             const int* __restrict__ cb,
                             float* __restrict__ out, int OD) {
  int o = blockIdx.x * 2 + (threadIdx.x >> 7);
  int b = threadIdx.x & 127;
  if (o >= OD) return;
  int ia = ca[o], ib = cb[o];
  float4 c = ((const float4*)coef)[o];
  float xa = xin[ia * B_SZ + b];
  float xb = xin[ib * B_SZ + b];
  out[o * B_SZ + b] = c.x + c.y * xa + c.z * xb + c.w * (xa * xb);
}

// fc3 [10240][128] -> out[b*10+cls] = sum_t fc3[cls*1024+t][b] / 10
__global__ void reduce_cls(const float* __restrict__ fc3, float* __restrict__ out) {
  int cls = blockIdx.x >> 5;
  int chunk = blockIdx.x & 31;
  int b = threadIdx.x;
  const float* base = fc3 + (cls * 1024 + chunk * 32) * B_SZ + b;
  float s = 0.f;
#pragma unroll
  for (int t = 0; t < 32; ++t) s += base[t * B_SZ];
  atomicAdd(&out[b * 10 + cls], s * 0.1f);
}

extern "C" void kernel_launch(void* const* d_in, const int* in_sizes, int n_in,
                              void* d_out, int out_size, void* d_ws, size_t ws_size,
                              hipStream_t stream) {
  const float* x   = (const float*)d_in[0];
  const float* w1  = (const float*)d_in[1];
  const float* w2  = (const float*)d_in[2];
  const float* w3  = (const float*)d_in[3];
  const float* w4  = (const float*)d_in[4];
  const float* fw1 = (const float*)d_in[5];
  const float* fw2 = (const float*)d_in[6];
  const float* fw3 = (const float*)d_in[7];
  const int* l1  = (const int*)d_in[8];
  const int* l2  = (const int*)d_in[9];
  const int* l3  = (const int*)d_in[10];
  const int* l4  = (const int*)d_in[11];
  const int* ca1 = (const int*)d_in[12];
  const int* cb1 = (const int*)d_in[13];
  const int* ca2 = (const int*)d_in[14];
  const int* cb2 = (const int*)d_in[15];
  const int* ca3 = (const int*)d_in[16];
  const int* cb3 = (const int*)d_in[17];

  float* ws = (float*)d_ws;
  // coef region: contiguous float4[78464] = 313,856 floats
  float* coef = ws;
  float* cC1 = coef;                 // 128 gates
  float* cC2 = cC1 + 128 * 4;
  float* cC3 = cC2 + 512 * 4;
  float* cC4 = cC3 + 2048 * 4;
  float* cF1 = cC4 + 4096 * 4;
  float* cF2 = cF1 + 40960 * 4;
  float* cF3 = cF2 + 20480 * 4;
  float* xb   = coef + 313856;       // 9*1024*128 = 1,179,648
  float* bufA = xb + 1179648;        // 5,242,880 (max stage: fc1 out)
  float* bufB = bufA + 5242880;      // 5,242,880
  // total ~ 52 MB

  make_coef_all<<<307, 256, 0, stream>>>(w1, w2, w3, w4, fw1, fw2, fw3, coef,
                                         (float*)d_out);
  binarize_transpose<<<96, 256, 0, stream>>>(x, xb);

  conv_tree_pool_fm<<<4096, 256, 0, stream>>>(xb,   cC1, l1, bufA,   9, 32, 32,   32);
  conv_tree_pool_fm<<<4096, 256, 0, stream>>>(bufA, cC2, l2, bufB,  32, 16, 16,  128);
  conv_tree_pool_fm<<<4096, 256, 0, stream>>>(bufB, cC3, l3, bufA, 128,  8,  8,  512);
  conv_tree_pool_fm<<<2048, 256, 0, stream>>>(bufA, cC4, l4, bufB, 512,  4,  4, 1024);

  difflogic_fc<<<20480, 256, 0, stream>>>(bufB, cF1, ca1, cb1, bufA, 40960);
  difflogic_fc<<<10240, 256, 0, stream>>>(bufA, cF2, ca2, cb2, bufB, 20480);
  difflogic_fc<<<5120, 256, 0, stream>>>(bufB, cF3, ca3, cb3, bufA, 10240);

  reduce_cls<<<320, 128, 0, stream>>>(bufA, (float*)d_out);
}